// Round 3
// baseline (754.594 us; speedup 1.0000x reference)
//
#include <hip/hip_runtime.h>
#include <hip/hip_bf16.h>

// SlowLSTM on MI355X (gfx950). B=4096, D=H=2048.
// Round 3: inputs bf16 (runtime dual-dtype kept as insurance), OUTPUT FP32
// (root cause of round-2 absmax 4.46: fp32 out buffer read as floats).
// Kernel 1: transpose 8 weight mats -> WT[g][n][kcat] bf16 in d_ws (64 MiB).
// Kernel 2: fused GEMM (128m x 32n x 4 gates, mfma 16x16x32 bf16, register
// staging) + LSTM epilogue, fp32 stores.

typedef unsigned short u16;
typedef __attribute__((ext_vector_type(4))) unsigned short u16x4;
typedef __attribute__((ext_vector_type(8))) unsigned short u16x8;
typedef __attribute__((ext_vector_type(8))) __bf16 bf16x8;
typedef __attribute__((ext_vector_type(4))) float f32x4;

#define BH_TOTAL (4096 * 2048)

__device__ __forceinline__ float b2f(u16 u) {
  union { unsigned int i; float f; } v; v.i = ((unsigned int)u) << 16; return v.f;
}
__device__ __forceinline__ u16 f2b(float f) {
  union { float f; unsigned int i; } v; v.f = f;
  unsigned int r = v.i + 0x7fffu + ((v.i >> 16) & 1u);  // RNE
  return (u16)(r >> 16);
}
__device__ __forceinline__ float sigmoidf_(float x) {
  return 1.0f / (1.0f + __expf(-x));
}

// fp32 read as u16 shows mantissa halves with huge "bf16 exponents";
// N(0,1)-scale bf16 never has exponent >= 0x90 (|v| >= 2^17).
__device__ __forceinline__ bool input_is_f32(const u16* Xu) {
  const int lane = threadIdx.x & 63;
  unsigned bad = 0;
#pragma unroll
  for (int j = 0; j < 4; ++j) {
    unsigned u = Xu[lane + (j << 6)];
    bad |= (((u >> 7) & 0xFFu) >= 0x90u) ? 1u : 0u;
  }
  return __any((int)bad) != 0;
}

// ---------------- Kernel 1: weight transpose -> WT[g][n][kcat] (bf16) ----
// grid 8192 x 256. m8 = bid>>10 = 2*g + phase (0=x,1=h). 64x64 tiles.
template <bool F32>
__global__ __launch_bounds__(256) void wt_transpose_kernel(
    const void* __restrict__ w0, const void* __restrict__ w1,
    const void* __restrict__ w2, const void* __restrict__ w3,
    const void* __restrict__ w4, const void* __restrict__ w5,
    const void* __restrict__ w6, const void* __restrict__ w7,
    u16* __restrict__ WT, const u16* __restrict__ Xu) {
  if (input_is_f32(Xu) != F32) return;
  __shared__ u16 tile[64][65];
  const int bid = blockIdx.x;
  const int m8 = bid >> 10;
  const void* srcs[8] = {w0, w1, w2, w3, w4, w5, w6, w7};
  const int g = m8 >> 1, ph = m8 & 1;
  const int tt = bid & 1023;
  const int k0 = (tt >> 5) << 6;
  const int n0 = (tt & 31) << 6;
  const int t = threadIdx.x;

#pragma unroll
  for (int i = 0; i < 4; ++i) {
    const int q = t + (i << 8);
    const int row = q >> 4;        // k within tile
    const int cx = (q & 15) << 2;  // n within tile (4 elems)
    if (F32) {
      const float* src = (const float*)srcs[m8];
      f32x4 v = *(const f32x4*)(src + (size_t)(k0 + row) * 2048 + n0 + cx);
      tile[row][cx + 0] = f2b(v[0]);
      tile[row][cx + 1] = f2b(v[1]);
      tile[row][cx + 2] = f2b(v[2]);
      tile[row][cx + 3] = f2b(v[3]);
    } else {
      const u16* src = (const u16*)srcs[m8];
      u16x4 v = *(const u16x4*)(src + (size_t)(k0 + row) * 2048 + n0 + cx);
      tile[row][cx + 0] = v[0];
      tile[row][cx + 1] = v[1];
      tile[row][cx + 2] = v[2];
      tile[row][cx + 3] = v[3];
    }
  }
  __syncthreads();
  const size_t gbase = ((size_t)g << 23) + (size_t)ph * 2048 + k0;
#pragma unroll
  for (int i = 0; i < 4; ++i) {
    const int q = t + (i << 8);
    const int nrow = q >> 4;       // n within tile
    const int kx = (q & 15) << 2;  // k within tile (4 elems)
    u16x4 v;
    v[0] = tile[kx + 0][nrow];
    v[1] = tile[kx + 1][nrow];
    v[2] = tile[kx + 2][nrow];
    v[3] = tile[kx + 3][nrow];
    *(u16x4*)(WT + gbase + (size_t)(n0 + nrow) * 4096 + kx) = v;
  }
}

// ---------------- Kernel 2: fused GEMM + LSTM (fp32 out) ----------------
// grid 2048 = 32 m-tiles x 64 n-tiles; 256 thr = 4 waves (2 m x 2 n halves).
template <bool F32>
__global__ __launch_bounds__(256) void lstm_gemm_kernel(
    const void* __restrict__ Xp, const void* __restrict__ Hp,
    const void* __restrict__ Cp, const u16* __restrict__ WT,
    const void* __restrict__ bip, const void* __restrict__ bfp,
    const void* __restrict__ bop, const void* __restrict__ bcp,
    float* __restrict__ Out) {
  if (input_is_f32((const u16*)Xp) != F32) return;
  __shared__ u16 As[128 * 32];     // [m][k]
  __shared__ u16 Bs[4 * 32 * 32];  // [gate][n][k]

  const int t = threadIdx.x;
  const int wave = t >> 6;
  const int lane = t & 63;
  const int ln = lane & 15;
  const int quad = lane >> 4;
  const int wm = wave >> 1;
  const int wn = wave & 1;
  const int m0 = (blockIdx.x >> 6) << 7;
  const int n0 = (blockIdx.x & 63) << 5;

  f32x4 acc[4][4];
#pragma unroll
  for (int g = 0; g < 4; ++g)
#pragma unroll
    for (int im = 0; im < 4; ++im) acc[g][im] = (f32x4)0.0f;

  for (int kt = 0; kt < 128; ++kt) {
    const void* Asrc = (kt < 64) ? Xp : Hp;
    const int kk = (kt & 63) << 5;  // k offset in source
    const int kcat = kt << 5;       // k offset in WT rows
#pragma unroll
    for (int i = 0; i < 2; ++i) {
      const int c = t + (i << 8);
      const int row = m0 + (c >> 2);
      const int ko = kk + ((c & 3) << 3);
      u16x8 w;
      if (F32) {
        const float* p = (const float*)Asrc + (size_t)row * 2048 + ko;
        f32x4 v0 = *(const f32x4*)p;
        f32x4 v1 = *(const f32x4*)(p + 4);
        w[0] = f2b(v0[0]); w[1] = f2b(v0[1]); w[2] = f2b(v0[2]); w[3] = f2b(v0[3]);
        w[4] = f2b(v1[0]); w[5] = f2b(v1[1]); w[6] = f2b(v1[2]); w[7] = f2b(v1[3]);
      } else {
        w = *(const u16x8*)((const u16*)Asrc + (size_t)row * 2048 + ko);
      }
      *(u16x8*)(As + c * 8) = w;
    }
#pragma unroll
    for (int i = 0; i < 2; ++i) {
      const int c = t + (i << 8);
      const int g = c >> 7;
      const int n = (c & 127) >> 2;
      const int kc = (c & 3) << 3;
      *(u16x8*)(Bs + c * 8) = *(const u16x8*)(
          WT + ((size_t)g << 23) + (size_t)(n0 + n) * 4096 + kcat + kc);
    }
    __syncthreads();

    bf16x8 a[4], b[4];
    const bf16x8* As8 = (const bf16x8*)As;
    const bf16x8* Bs8 = (const bf16x8*)Bs;
#pragma unroll
    for (int im = 0; im < 4; ++im)
      a[im] = As8[(wm * 64 + im * 16 + ln) * 4 + quad];
#pragma unroll
    for (int g = 0; g < 4; ++g)
      b[g] = Bs8[(g * 32 + wn * 16 + ln) * 4 + quad];
#pragma unroll
    for (int g = 0; g < 4; ++g)
#pragma unroll
      for (int im = 0; im < 4; ++im)
        acc[g][im] = __builtin_amdgcn_mfma_f32_16x16x32_bf16(a[im], b[g],
                                                             acc[g][im], 0, 0, 0);
    __syncthreads();
  }

  // Epilogue: bias + activations + elementwise; FP32 stores.
  const int ncol = n0 + wn * 16 + ln;
  float Bi, Bf, Bo, Bc;
  if (F32) {
    Bi = ((const float*)bip)[ncol]; Bf = ((const float*)bfp)[ncol];
    Bo = ((const float*)bop)[ncol]; Bc = ((const float*)bcp)[ncol];
  } else {
    Bi = b2f(((const u16*)bip)[ncol]); Bf = b2f(((const u16*)bfp)[ncol]);
    Bo = b2f(((const u16*)bop)[ncol]); Bc = b2f(((const u16*)bcp)[ncol]);
  }
#pragma unroll
  for (int im = 0; im < 4; ++im) {
#pragma unroll
    for (int r = 0; r < 4; ++r) {
      const int m = m0 + wm * 64 + im * 16 + quad * 4 + r;
      const size_t idx = (size_t)m * 2048 + ncol;
      const float gi = sigmoidf_(acc[0][im][r] + Bi);
      const float gf = sigmoidf_(acc[1][im][r] + Bf);
      const float go = sigmoidf_(acc[2][im][r] + Bo);
      const float gc = tanhf(acc[3][im][r] + Bc);
      const float c_in = F32 ? ((const float*)Cp)[idx] : b2f(((const u16*)Cp)[idx]);
      const float ct = gf * c_in + gi * gc;
      const float ht = go * tanhf(ct);
      Out[idx] = ht;             // h_t (fp32)
      Out[idx + BH_TOTAL] = ct;  // c_t (fp32)
    }
  }
}

extern "C" void kernel_launch(void* const* d_in, const int* in_sizes, int n_in,
                              void* d_out, int out_size, void* d_ws,
                              size_t ws_size, hipStream_t stream) {
  const u16* Xu = (const u16*)d_in[0];
  u16* WT = (u16*)d_ws;  // 64 MiB

  hipLaunchKernelGGL((wt_transpose_kernel<false>), dim3(8192), dim3(256), 0,
                     stream, d_in[3], d_in[4], d_in[5], d_in[6], d_in[7],
                     d_in[8], d_in[9], d_in[10], WT, Xu);
  hipLaunchKernelGGL((wt_transpose_kernel<true>), dim3(8192), dim3(256), 0,
                     stream, d_in[3], d_in[4], d_in[5], d_in[6], d_in[7],
                     d_in[8], d_in[9], d_in[10], WT, Xu);
  hipLaunchKernelGGL((lstm_gemm_kernel<false>), dim3(2048), dim3(256), 0,
                     stream, d_in[0], d_in[1], d_in[2], WT, d_in[11], d_in[12],
                     d_in[13], d_in[14], (float*)d_out);
  hipLaunchKernelGGL((lstm_gemm_kernel<true>), dim3(2048), dim3(256), 0,
                     stream, d_in[0], d_in[1], d_in[2], WT, d_in[11], d_in[12],
                     d_in[13], d_in[14], (float*)d_out);
}